// Round 7
// baseline (1475.504 us; speedup 1.0000x reference)
//
#include <hip/hip_runtime.h>

// MonotoneiResBlock: B=131072 rows, D=64, H=256.
//   forward:  w <- sqrt2*x - tanh(w@W1)@W2   (10 iters; Lip~0.49)
//   y = x - sqrt2*g_last
//   logdet = -2 * sum_{k odd<=9} eps^T J^k eps,   J v = (sech^2(w@W1) o (v@W1)) @ W2
// Transposed MFMA GEMMs, shared K-permutation pi so GEMM1's D-frag feeds GEMM2 as B-frag.
// Round-7: FIT THE 128-VGPR BUDGET (allocator pins 128 for 512-thread blocks; waves_per_eu/LDS
// hints don't move it - rounds 4/5/6 evidence). 16 rows/wave -> peak live ~100 regs, zero spill.
// Keeps: fused hbk GEMM1->GEMM2 (no [8] array), scalar-p Neumann (no s/tt), frag-carried w.
// d_out FLOAT32: y = 131072*64, then logdet = 131072.

typedef __attribute__((ext_vector_type(8))) short bf16x8;
typedef __attribute__((ext_vector_type(4))) float f32x4;
typedef __attribute__((ext_vector_type(4))) unsigned int u32x4;

#define SQRT2F 1.41421356237309515f
#define INVSQRT2F 0.70710678118654752f
#define NITER 10

__device__ __forceinline__ unsigned int pack2(float a, float b) {
    unsigned int ua = __builtin_bit_cast(unsigned int, a);
    unsigned int ub = __builtin_bit_cast(unsigned int, b);
    return ((ua + 0x8000u) >> 16) | ((ub + 0x8000u) & 0xFFFF0000u);
}
__device__ __forceinline__ float bf_lo(unsigned int u) { return __builtin_bit_cast(float, u << 16); }
__device__ __forceinline__ float bf_hi(unsigned int u) { return __builtin_bit_cast(float, u & 0xFFFF0000u); }
__device__ __forceinline__ float fast_tanh(float xx) {
    float a = __expf(xx + xx);
    float r = __builtin_amdgcn_rcpf(a + 1.0f);
    return fmaf(-2.0f, r, 1.0f);
}
__device__ __forceinline__ bf16x8 packfrag4(f32x4 a, f32x4 b) {
    u32x4 r;
    r[0] = pack2(a[0], a[1]); r[1] = pack2(a[2], a[3]);
    r[2] = pack2(b[0], b[1]); r[3] = pack2(b[2], b[3]);
    return __builtin_bit_cast(bf16x8, r);
}

// Fused pass over 16 rows. MODE 0: tanh. MODE 1: tanh + capture dd, skip GEMM2. MODE 2: dd-multiply.
template <int MODE>
__device__ __forceinline__ void fused_pass16(const u32x4* __restrict__ sW1p, const u32x4* __restrict__ sW2p,
                                             int lane, bf16x8 b0, bf16x8 b1,
                                             unsigned int (&dpk)[16][2], f32x4 (&g)[4]) {
    f32x4 zz = {0.f, 0.f, 0.f, 0.f};
    if constexpr (MODE != 1) {
#pragma unroll
        for (int t = 0; t < 4; ++t) g[t] = zz;
    }
#pragma unroll
    for (int kk = 0; kk < 8; ++kk) {
        u32x4 hbk;
#pragma unroll
        for (int sub = 0; sub < 2; ++sub) {
            const int m = 2 * kk + sub;
            f32x4 acc = zz;
            acc = __builtin_amdgcn_mfma_f32_16x16x32_bf16(
                __builtin_bit_cast(bf16x8, sW1p[(m * 2 + 0) * 64 + lane]), b0, acc, 0, 0, 0);
            acc = __builtin_amdgcn_mfma_f32_16x16x32_bf16(
                __builtin_bit_cast(bf16x8, sW1p[(m * 2 + 1) * 64 + lane]), b1, acc, 0, 0, 0);
            float h0, h1, h2, h3;
            if constexpr (MODE == 2) {
                h0 = acc[0] * bf_lo(dpk[m][0]);
                h1 = acc[1] * bf_hi(dpk[m][0]);
                h2 = acc[2] * bf_lo(dpk[m][1]);
                h3 = acc[3] * bf_hi(dpk[m][1]);
            } else {
                h0 = fast_tanh(acc[0]); h1 = fast_tanh(acc[1]);
                h2 = fast_tanh(acc[2]); h3 = fast_tanh(acc[3]);
                if constexpr (MODE == 1) {
                    dpk[m][0] = pack2(fmaf(-h0, h0, 1.0f), fmaf(-h1, h1, 1.0f));
                    dpk[m][1] = pack2(fmaf(-h2, h2, 1.0f), fmaf(-h3, h3, 1.0f));
                }
            }
            if constexpr (MODE != 1) {
                hbk[2 * sub + 0] = pack2(h0, h1);
                hbk[2 * sub + 1] = pack2(h2, h3);
            }
        }
        if constexpr (MODE != 1) {
            bf16x8 bh = __builtin_bit_cast(bf16x8, hbk);
#pragma unroll
            for (int t = 0; t < 4; ++t) {
                bf16x8 w2 = __builtin_bit_cast(bf16x8, sW2p[(t * 8 + kk) * 64 + lane]);
                g[t] = __builtin_amdgcn_mfma_f32_16x16x32_bf16(w2, bh, g[t], 0, 0, 0);
            }
        }
    }
}

__global__ void monot_kernel(
    const float* __restrict__ x, const float* __restrict__ eps,
    const float* __restrict__ W1, const float* __restrict__ W2,
    float* __restrict__ out) {
    __shared__ u32x4 sW1p[2048];  // [m0(16)][kk(2)][lane(64)] A-frags of W1^T, pi-permuted K
    __shared__ u32x4 sW2p[2048];  // [m0(4)][kk(8)][lane(64)]  A-frags of W2^T

    const int tid = threadIdx.x;
    const int lane = tid & 63;
    const int wv = tid >> 6;
    const int c = lane & 15;
    const int q = lane >> 4;

    // ---- pack weights into LDS (A-frag layout; pi(q,j) = 4q + (j&3) + 16*(j>>2)) ----
#pragma unroll
    for (int e0 = 0; e0 < 4; ++e0) {
        int idx = e0 * 512 + tid;  // W1 entries
        int l = idx & 63;
        int lq = l >> 4, lc = l & 15;
        int m0 = idx >> 7;
        int kk = (idx >> 6) & 1;
        float v[8];
#pragma unroll
        for (int j = 0; j < 8; ++j) {
            int kp = 32 * kk + 4 * lq + (j & 3) + ((j >> 2) << 4);
            v[j] = W1[kp * 256 + 16 * m0 + lc];  // W1^T[16m0+lc][kp]
        }
        u32x4 pk;
        pk[0] = pack2(v[0], v[1]); pk[1] = pack2(v[2], v[3]);
        pk[2] = pack2(v[4], v[5]); pk[3] = pack2(v[6], v[7]);
        sW1p[idx] = pk;
    }
#pragma unroll
    for (int e0 = 0; e0 < 4; ++e0) {
        int idx = e0 * 512 + tid;  // W2 entries
        int l = idx & 63;
        int lq = l >> 4, lc = l & 15;
        int m0 = idx >> 9;
        int kk = (idx >> 6) & 7;
        float v[8];
#pragma unroll
        for (int j = 0; j < 8; ++j) {
            int kp = 32 * kk + 4 * lq + (j & 3) + ((j >> 2) << 4);
            v[j] = W2[kp * 64 + 16 * m0 + lc];  // W2^T[16m0+lc][kp]
        }
        u32x4 pk;
        pk[0] = pack2(v[0], v[1]); pk[1] = pack2(v[2], v[3]);
        pk[2] = pack2(v[4], v[5]); pk[3] = pack2(v[6], v[7]);
        sW2p[idx] = pk;
    }
    __syncthreads();

    const int row = blockIdx.x * 128 + wv * 16 + c;
    const float* xr = x + (size_t)row * 64;

    unsigned int dpk[16][2];  // dd packed bf16 (filled by MODE-1 pass)
    f32x4 sx[4];              // sqrt2 * x, lane dims 16m+4q+r
    bf16x8 b0, b1;            // bf16 frags of current w
    {
        f32x4 t0 = *(const f32x4*)(xr + 0 + 4 * q);
        f32x4 t1 = *(const f32x4*)(xr + 16 + 4 * q);
        f32x4 t2 = *(const f32x4*)(xr + 32 + 4 * q);
        f32x4 t3 = *(const f32x4*)(xr + 48 + 4 * q);
#pragma unroll
        for (int r = 0; r < 4; ++r) {
            sx[0][r] = SQRT2F * t0[r]; sx[1][r] = SQRT2F * t1[r];
            sx[2][r] = SQRT2F * t2[r]; sx[3][r] = SQRT2F * t3[r];
        }
        b0 = packfrag4(sx[0], sx[1]);
        b1 = packfrag4(sx[2], sx[3]);
    }

    f32x4 g[4];
    // ---- fixed-point iterations: w_next = sx - g(w); frags hold w ----
#pragma unroll 1
    for (int it = 0; it < NITER; ++it) {
        fused_pass16<0>(sW1p, sW2p, lane, b0, b1, dpk, g);
        f32x4 w0 = sx[0] - g[0], w1 = sx[1] - g[1];
        f32x4 w2 = sx[2] - g[2], w3 = sx[3] - g[3];
        b0 = packfrag4(w0, w1);
        b1 = packfrag4(w2, w3);
    }

    // ---- y = x - sqrt2*g_last = inv_sqrt2*sx - sqrt2*g ----
#pragma unroll
    for (int m = 0; m < 4; ++m) {
        f32x4 y;
#pragma unroll
        for (int r = 0; r < 4; ++r) y[r] = fmaf(INVSQRT2F, sx[m][r], -SQRT2F * g[m][r]);
        *(f32x4*)(out + (size_t)row * 64 + 16 * m + 4 * q) = y;
    }

    // ---- dd = sech^2(w_final @ W1); frags already hold w_final ----
    fused_pass16<1>(sW1p, sW2p, lane, b0, b1, dpk, g);

    // ---- Neumann: p = sum_{k odd<=9} eps.(J^k eps); logdet = -2p ----
    f32x4 ew[4];
    {
        const float* er = eps + (size_t)row * 64;
#pragma unroll
        for (int m = 0; m < 4; ++m) ew[m] = *(const f32x4*)(er + 16 * m + 4 * q);
    }
    b0 = packfrag4(ew[0], ew[1]);
    b1 = packfrag4(ew[2], ew[3]);
    float p = 0.f;
#pragma unroll 1
    for (int k = 1; k <= 9; ++k) {
        fused_pass16<2>(sW1p, sW2p, lane, b0, b1, dpk, g);
        if (k & 1) {
#pragma unroll
            for (int m = 0; m < 4; ++m)
#pragma unroll
                for (int r = 0; r < 4; ++r) p = fmaf(ew[m][r], g[m][r], p);
        }
        b0 = packfrag4(g[0], g[1]);
        b1 = packfrag4(g[2], g[3]);
    }
    p += __shfl_xor(p, 16);
    p += __shfl_xor(p, 32);
    p *= -2.0f;
    if (lane < 16) out[(size_t)8388608 + row] = p;
}

extern "C" void kernel_launch(void* const* d_in, const int* in_sizes, int n_in,
                              void* d_out, int out_size, void* d_ws, size_t ws_size,
                              hipStream_t stream) {
    const float* x = (const float*)d_in[0];
    const float* eps = (const float*)d_in[1];
    const float* W1 = (const float*)d_in[2];
    const float* W2 = (const float*)d_in[3];
    float* out = (float*)d_out;
    // 131072 rows / (8 waves * 16 rows) = 1024 blocks
    monot_kernel<<<dim3(1024), dim3(512), 0, stream>>>(x, eps, W1, W2, out);
}

// Round 8
// 571.223 us; speedup vs baseline: 2.5831x; 2.5831x over previous
//
#include <hip/hip_runtime.h>

// MonotoneiResBlock: B=131072 rows, D=64, H=256.
//   forward:  w <- sqrt2*x - tanh(w@W1)@W2   (10 iters; Lip~0.49)
//   y = x - sqrt2*g_last
//   logdet = -2 * sum_{k odd<=9} eps^T J^k eps,   J v = (sech^2(w@W1) o (v@W1)) @ W2
// Transposed MFMA GEMMs, shared K-permutation pi so GEMM1's D-frag feeds GEMM2 as B-frag.
// Round-8: round-7's lean 16-rows/wave body (live ~110 regs) + __launch_bounds__(512,2), the only
// setting that yields a 128-VGPR budget on this toolchain (allocator map: default/(512,4)->64,
// (512,2)->128, (512,1)->128, waves_per_eu attr ignored). First spill-free configuration.
// d_out FLOAT32: y = 131072*64, then logdet = 131072.

typedef __attribute__((ext_vector_type(8))) short bf16x8;
typedef __attribute__((ext_vector_type(4))) float f32x4;
typedef __attribute__((ext_vector_type(4))) unsigned int u32x4;

#define SQRT2F 1.41421356237309515f
#define INVSQRT2F 0.70710678118654752f
#define NITER 10

__device__ __forceinline__ unsigned int pack2(float a, float b) {
    unsigned int ua = __builtin_bit_cast(unsigned int, a);
    unsigned int ub = __builtin_bit_cast(unsigned int, b);
    return ((ua + 0x8000u) >> 16) | ((ub + 0x8000u) & 0xFFFF0000u);
}
__device__ __forceinline__ float bf_lo(unsigned int u) { return __builtin_bit_cast(float, u << 16); }
__device__ __forceinline__ float bf_hi(unsigned int u) { return __builtin_bit_cast(float, u & 0xFFFF0000u); }
__device__ __forceinline__ float fast_tanh(float xx) {
    float a = __expf(xx + xx);
    float r = __builtin_amdgcn_rcpf(a + 1.0f);
    return fmaf(-2.0f, r, 1.0f);
}
__device__ __forceinline__ bf16x8 packfrag4(f32x4 a, f32x4 b) {
    u32x4 r;
    r[0] = pack2(a[0], a[1]); r[1] = pack2(a[2], a[3]);
    r[2] = pack2(b[0], b[1]); r[3] = pack2(b[2], b[3]);
    return __builtin_bit_cast(bf16x8, r);
}

// Fused pass over 16 rows. MODE 0: tanh. MODE 1: tanh + capture dd, skip GEMM2. MODE 2: dd-multiply.
template <int MODE>
__device__ __forceinline__ void fused_pass16(const u32x4* __restrict__ sW1p, const u32x4* __restrict__ sW2p,
                                             int lane, bf16x8 b0, bf16x8 b1,
                                             unsigned int (&dpk)[16][2], f32x4 (&g)[4]) {
    f32x4 zz = {0.f, 0.f, 0.f, 0.f};
    if constexpr (MODE != 1) {
#pragma unroll
        for (int t = 0; t < 4; ++t) g[t] = zz;
    }
#pragma unroll
    for (int kk = 0; kk < 8; ++kk) {
        u32x4 hbk;
#pragma unroll
        for (int sub = 0; sub < 2; ++sub) {
            const int m = 2 * kk + sub;
            f32x4 acc = zz;
            acc = __builtin_amdgcn_mfma_f32_16x16x32_bf16(
                __builtin_bit_cast(bf16x8, sW1p[(m * 2 + 0) * 64 + lane]), b0, acc, 0, 0, 0);
            acc = __builtin_amdgcn_mfma_f32_16x16x32_bf16(
                __builtin_bit_cast(bf16x8, sW1p[(m * 2 + 1) * 64 + lane]), b1, acc, 0, 0, 0);
            float h0, h1, h2, h3;
            if constexpr (MODE == 2) {
                h0 = acc[0] * bf_lo(dpk[m][0]);
                h1 = acc[1] * bf_hi(dpk[m][0]);
                h2 = acc[2] * bf_lo(dpk[m][1]);
                h3 = acc[3] * bf_hi(dpk[m][1]);
            } else {
                h0 = fast_tanh(acc[0]); h1 = fast_tanh(acc[1]);
                h2 = fast_tanh(acc[2]); h3 = fast_tanh(acc[3]);
                if constexpr (MODE == 1) {
                    dpk[m][0] = pack2(fmaf(-h0, h0, 1.0f), fmaf(-h1, h1, 1.0f));
                    dpk[m][1] = pack2(fmaf(-h2, h2, 1.0f), fmaf(-h3, h3, 1.0f));
                }
            }
            if constexpr (MODE != 1) {
                hbk[2 * sub + 0] = pack2(h0, h1);
                hbk[2 * sub + 1] = pack2(h2, h3);
            }
        }
        if constexpr (MODE != 1) {
            bf16x8 bh = __builtin_bit_cast(bf16x8, hbk);
#pragma unroll
            for (int t = 0; t < 4; ++t) {
                bf16x8 w2 = __builtin_bit_cast(bf16x8, sW2p[(t * 8 + kk) * 64 + lane]);
                g[t] = __builtin_amdgcn_mfma_f32_16x16x32_bf16(w2, bh, g[t], 0, 0, 0);
            }
        }
    }
}

__global__ __launch_bounds__(512, 2) void monot_kernel(
    const float* __restrict__ x, const float* __restrict__ eps,
    const float* __restrict__ W1, const float* __restrict__ W2,
    float* __restrict__ out) {
    __shared__ u32x4 sW1p[2048];  // [m0(16)][kk(2)][lane(64)] A-frags of W1^T, pi-permuted K
    __shared__ u32x4 sW2p[2048];  // [m0(4)][kk(8)][lane(64)]  A-frags of W2^T

    const int tid = threadIdx.x;
    const int lane = tid & 63;
    const int wv = tid >> 6;
    const int c = lane & 15;
    const int q = lane >> 4;

    // ---- pack weights into LDS (A-frag layout; pi(q,j) = 4q + (j&3) + 16*(j>>2)) ----
#pragma unroll
    for (int e0 = 0; e0 < 4; ++e0) {
        int idx = e0 * 512 + tid;  // W1 entries
        int l = idx & 63;
        int lq = l >> 4, lc = l & 15;
        int m0 = idx >> 7;
        int kk = (idx >> 6) & 1;
        float v[8];
#pragma unroll
        for (int j = 0; j < 8; ++j) {
            int kp = 32 * kk + 4 * lq + (j & 3) + ((j >> 2) << 4);
            v[j] = W1[kp * 256 + 16 * m0 + lc];  // W1^T[16m0+lc][kp]
        }
        u32x4 pk;
        pk[0] = pack2(v[0], v[1]); pk[1] = pack2(v[2], v[3]);
        pk[2] = pack2(v[4], v[5]); pk[3] = pack2(v[6], v[7]);
        sW1p[idx] = pk;
    }
#pragma unroll
    for (int e0 = 0; e0 < 4; ++e0) {
        int idx = e0 * 512 + tid;  // W2 entries
        int l = idx & 63;
        int lq = l >> 4, lc = l & 15;
        int m0 = idx >> 9;
        int kk = (idx >> 6) & 7;
        float v[8];
#pragma unroll
        for (int j = 0; j < 8; ++j) {
            int kp = 32 * kk + 4 * lq + (j & 3) + ((j >> 2) << 4);
            v[j] = W2[kp * 64 + 16 * m0 + lc];  // W2^T[16m0+lc][kp]
        }
        u32x4 pk;
        pk[0] = pack2(v[0], v[1]); pk[1] = pack2(v[2], v[3]);
        pk[2] = pack2(v[4], v[5]); pk[3] = pack2(v[6], v[7]);
        sW2p[idx] = pk;
    }
    __syncthreads();

    const int row = blockIdx.x * 128 + wv * 16 + c;
    const float* xr = x + (size_t)row * 64;

    unsigned int dpk[16][2];  // dd packed bf16 (filled by MODE-1 pass)
    f32x4 sx[4];              // sqrt2 * x, lane dims 16m+4q+r
    bf16x8 b0, b1;            // bf16 frags of current w
    {
        f32x4 t0 = *(const f32x4*)(xr + 0 + 4 * q);
        f32x4 t1 = *(const f32x4*)(xr + 16 + 4 * q);
        f32x4 t2 = *(const f32x4*)(xr + 32 + 4 * q);
        f32x4 t3 = *(const f32x4*)(xr + 48 + 4 * q);
#pragma unroll
        for (int r = 0; r < 4; ++r) {
            sx[0][r] = SQRT2F * t0[r]; sx[1][r] = SQRT2F * t1[r];
            sx[2][r] = SQRT2F * t2[r]; sx[3][r] = SQRT2F * t3[r];
        }
        b0 = packfrag4(sx[0], sx[1]);
        b1 = packfrag4(sx[2], sx[3]);
    }

    f32x4 g[4];
    // ---- fixed-point iterations: w_next = sx - g(w); frags hold w ----
#pragma unroll 1
    for (int it = 0; it < NITER; ++it) {
        fused_pass16<0>(sW1p, sW2p, lane, b0, b1, dpk, g);
        f32x4 w0 = sx[0] - g[0], w1 = sx[1] - g[1];
        f32x4 w2 = sx[2] - g[2], w3 = sx[3] - g[3];
        b0 = packfrag4(w0, w1);
        b1 = packfrag4(w2, w3);
    }

    // ---- y = x - sqrt2*g_last = inv_sqrt2*sx - sqrt2*g ----
#pragma unroll
    for (int m = 0; m < 4; ++m) {
        f32x4 y;
#pragma unroll
        for (int r = 0; r < 4; ++r) y[r] = fmaf(INVSQRT2F, sx[m][r], -SQRT2F * g[m][r]);
        *(f32x4*)(out + (size_t)row * 64 + 16 * m + 4 * q) = y;
    }

    // ---- dd = sech^2(w_final @ W1); frags already hold w_final ----
    fused_pass16<1>(sW1p, sW2p, lane, b0, b1, dpk, g);

    // ---- Neumann: p = sum_{k odd<=9} eps.(J^k eps); logdet = -2p ----
    f32x4 ew[4];
    {
        const float* er = eps + (size_t)row * 64;
#pragma unroll
        for (int m = 0; m < 4; ++m) ew[m] = *(const f32x4*)(er + 16 * m + 4 * q);
    }
    b0 = packfrag4(ew[0], ew[1]);
    b1 = packfrag4(ew[2], ew[3]);
    float p = 0.f;
#pragma unroll 1
    for (int k = 1; k <= 9; ++k) {
        fused_pass16<2>(sW1p, sW2p, lane, b0, b1, dpk, g);
        if (k & 1) {
#pragma unroll
            for (int m = 0; m < 4; ++m)
#pragma unroll
                for (int r = 0; r < 4; ++r) p = fmaf(ew[m][r], g[m][r], p);
        }
        b0 = packfrag4(g[0], g[1]);
        b1 = packfrag4(g[2], g[3]);
    }
    p += __shfl_xor(p, 16);
    p += __shfl_xor(p, 32);
    p *= -2.0f;
    if (lane < 16) out[(size_t)8388608 + row] = p;
}

extern "C" void kernel_launch(void* const* d_in, const int* in_sizes, int n_in,
                              void* d_out, int out_size, void* d_ws, size_t ws_size,
                              hipStream_t stream) {
    const float* x = (const float*)d_in[0];
    const float* eps = (const float*)d_in[1];
    const float* W1 = (const float*)d_in[2];
    const float* W2 = (const float*)d_in[3];
    float* out = (float*)d_out;
    // 131072 rows / (8 waves * 16 rows) = 1024 blocks
    monot_kernel<<<dim3(1024), dim3(512), 0, stream>>>(x, eps, W1, W2, out);
}

// Round 9
// 253.696 us; speedup vs baseline: 5.8160x; 2.2516x over previous
//
#include <hip/hip_runtime.h>

// MonotoneiResBlock: B=131072 rows, D=64, H=256.
//   forward:  w <- sqrt2*x - tanh(w@W1)@W2   (10 iters; Lip~0.49)
//   y = x - sqrt2*g_last
//   logdet = -2 * sum_{k odd<=9} eps^T J^k eps,   J v = (sech^2(w@W1) o (v@W1)) @ W2
// Transposed MFMA GEMMs, shared K-permutation pi so GEMM1's D-frag feeds GEMM2 as B-frag.
// Round-9: 256-thread blocks + __launch_bounds__(256,1) -> 1 wave/EU min -> 256-VGPR budget
// (512-thread blocks clamp to <=128: rounds 2-8 all spill-bound at 1.2-4 GB phantom HBM traffic).
// 32 rows/wave (round-6 verified body): weight A-frag ds_reads amortized over 2 row-groups.
// d_out FLOAT32: y = 131072*64, then logdet = 131072.

typedef __attribute__((ext_vector_type(8))) short bf16x8;
typedef __attribute__((ext_vector_type(4))) float f32x4;
typedef __attribute__((ext_vector_type(4))) unsigned int u32x4;

#define SQRT2F 1.41421356237309515f
#define INVSQRT2F 0.70710678118654752f
#define NITER 10

__device__ __forceinline__ unsigned int pack2(float a, float b) {
    unsigned int ua = __builtin_bit_cast(unsigned int, a);
    unsigned int ub = __builtin_bit_cast(unsigned int, b);
    return ((ua + 0x8000u) >> 16) | ((ub + 0x8000u) & 0xFFFF0000u);
}
__device__ __forceinline__ float bf_lo(unsigned int u) { return __builtin_bit_cast(float, u << 16); }
__device__ __forceinline__ float bf_hi(unsigned int u) { return __builtin_bit_cast(float, u & 0xFFFF0000u); }
__device__ __forceinline__ float fast_tanh(float xx) {
    float a = __expf(xx + xx);
    float r = __builtin_amdgcn_rcpf(a + 1.0f);
    return fmaf(-2.0f, r, 1.0f);
}
__device__ __forceinline__ bf16x8 packfrag4(f32x4 a, f32x4 b) {
    u32x4 r;
    r[0] = pack2(a[0], a[1]); r[1] = pack2(a[2], a[3]);
    r[2] = pack2(b[0], b[1]); r[3] = pack2(b[2], b[3]);
    return __builtin_bit_cast(bf16x8, r);
}

// Fused pass over 32 rows (two 16-row groups share every weight A-frag ds_read).
// MODE 0: tanh. MODE 1: tanh + capture dd, skip GEMM2 (g untouched). MODE 2: dd-multiply.
template <int MODE>
__device__ __forceinline__ void fused_pass32(const u32x4* __restrict__ sW1p, const u32x4* __restrict__ sW2p,
                                             int lane, bf16x8 b00, bf16x8 b01, bf16x8 b10, bf16x8 b11,
                                             unsigned int (&dpk)[2][16][2], f32x4 (&g)[2][4]) {
    f32x4 zz = {0.f, 0.f, 0.f, 0.f};
    if constexpr (MODE != 1) {
#pragma unroll
        for (int gi = 0; gi < 2; ++gi)
#pragma unroll
            for (int t = 0; t < 4; ++t) g[gi][t] = zz;
    }
#pragma unroll
    for (int kk = 0; kk < 8; ++kk) {
        u32x4 hbk0, hbk1;
#pragma unroll
        for (int sub = 0; sub < 2; ++sub) {
            const int m = 2 * kk + sub;
            u32x4 wA = sW1p[(m * 2 + 0) * 64 + lane];
            u32x4 wB = sW1p[(m * 2 + 1) * 64 + lane];
            f32x4 a0 = zz, a1 = zz;
            a0 = __builtin_amdgcn_mfma_f32_16x16x32_bf16(__builtin_bit_cast(bf16x8, wA), b00, a0, 0, 0, 0);
            a0 = __builtin_amdgcn_mfma_f32_16x16x32_bf16(__builtin_bit_cast(bf16x8, wB), b01, a0, 0, 0, 0);
            a1 = __builtin_amdgcn_mfma_f32_16x16x32_bf16(__builtin_bit_cast(bf16x8, wA), b10, a1, 0, 0, 0);
            a1 = __builtin_amdgcn_mfma_f32_16x16x32_bf16(__builtin_bit_cast(bf16x8, wB), b11, a1, 0, 0, 0);
            float h00, h01, h02, h03, h10, h11, h12, h13;
            if constexpr (MODE == 2) {
                h00 = a0[0] * bf_lo(dpk[0][m][0]);
                h01 = a0[1] * bf_hi(dpk[0][m][0]);
                h02 = a0[2] * bf_lo(dpk[0][m][1]);
                h03 = a0[3] * bf_hi(dpk[0][m][1]);
                h10 = a1[0] * bf_lo(dpk[1][m][0]);
                h11 = a1[1] * bf_hi(dpk[1][m][0]);
                h12 = a1[2] * bf_lo(dpk[1][m][1]);
                h13 = a1[3] * bf_hi(dpk[1][m][1]);
            } else {
                h00 = fast_tanh(a0[0]); h01 = fast_tanh(a0[1]);
                h02 = fast_tanh(a0[2]); h03 = fast_tanh(a0[3]);
                h10 = fast_tanh(a1[0]); h11 = fast_tanh(a1[1]);
                h12 = fast_tanh(a1[2]); h13 = fast_tanh(a1[3]);
                if constexpr (MODE == 1) {
                    dpk[0][m][0] = pack2(fmaf(-h00, h00, 1.0f), fmaf(-h01, h01, 1.0f));
                    dpk[0][m][1] = pack2(fmaf(-h02, h02, 1.0f), fmaf(-h03, h03, 1.0f));
                    dpk[1][m][0] = pack2(fmaf(-h10, h10, 1.0f), fmaf(-h11, h11, 1.0f));
                    dpk[1][m][1] = pack2(fmaf(-h12, h12, 1.0f), fmaf(-h13, h13, 1.0f));
                }
            }
            if constexpr (MODE != 1) {
                hbk0[2 * sub + 0] = pack2(h00, h01); hbk0[2 * sub + 1] = pack2(h02, h03);
                hbk1[2 * sub + 0] = pack2(h10, h11); hbk1[2 * sub + 1] = pack2(h12, h13);
            }
        }
        if constexpr (MODE != 1) {
            bf16x8 bh0 = __builtin_bit_cast(bf16x8, hbk0);
            bf16x8 bh1 = __builtin_bit_cast(bf16x8, hbk1);
#pragma unroll
            for (int t = 0; t < 4; ++t) {
                bf16x8 w2 = __builtin_bit_cast(bf16x8, sW2p[(t * 8 + kk) * 64 + lane]);
                g[0][t] = __builtin_amdgcn_mfma_f32_16x16x32_bf16(w2, bh0, g[0][t], 0, 0, 0);
                g[1][t] = __builtin_amdgcn_mfma_f32_16x16x32_bf16(w2, bh1, g[1][t], 0, 0, 0);
            }
        }
    }
}

__global__ __launch_bounds__(256, 1) void monot_kernel(
    const float* __restrict__ x, const float* __restrict__ eps,
    const float* __restrict__ W1, const float* __restrict__ W2,
    float* __restrict__ out) {
    __shared__ u32x4 sW1p[2048];  // [m0(16)][kk(2)][lane(64)] A-frags of W1^T, pi-permuted K
    __shared__ u32x4 sW2p[2048];  // [m0(4)][kk(8)][lane(64)]  A-frags of W2^T

    const int tid = threadIdx.x;
    const int lane = tid & 63;
    const int wv = tid >> 6;  // 0..3
    const int c = lane & 15;
    const int q = lane >> 4;

    // ---- pack weights into LDS (A-frag layout; pi(q,j) = 4q + (j&3) + 16*(j>>2)) ----
#pragma unroll
    for (int e0 = 0; e0 < 8; ++e0) {
        int idx = e0 * 256 + tid;  // W1 entries
        int l = idx & 63;
        int lq = l >> 4, lc = l & 15;
        int m0 = idx >> 7;
        int kk = (idx >> 6) & 1;
        float v[8];
#pragma unroll
        for (int j = 0; j < 8; ++j) {
            int kp = 32 * kk + 4 * lq + (j & 3) + ((j >> 2) << 4);
            v[j] = W1[kp * 256 + 16 * m0 + lc];  // W1^T[16m0+lc][kp]
        }
        u32x4 pk;
        pk[0] = pack2(v[0], v[1]); pk[1] = pack2(v[2], v[3]);
        pk[2] = pack2(v[4], v[5]); pk[3] = pack2(v[6], v[7]);
        sW1p[idx] = pk;
    }
#pragma unroll
    for (int e0 = 0; e0 < 8; ++e0) {
        int idx = e0 * 256 + tid;  // W2 entries
        int l = idx & 63;
        int lq = l >> 4, lc = l & 15;
        int m0 = idx >> 9;
        int kk = (idx >> 6) & 7;
        float v[8];
#pragma unroll
        for (int j = 0; j < 8; ++j) {
            int kp = 32 * kk + 4 * lq + (j & 3) + ((j >> 2) << 4);
            v[j] = W2[kp * 64 + 16 * m0 + lc];  // W2^T[16m0+lc][kp]
        }
        u32x4 pk;
        pk[0] = pack2(v[0], v[1]); pk[1] = pack2(v[2], v[3]);
        pk[2] = pack2(v[4], v[5]); pk[3] = pack2(v[6], v[7]);
        sW2p[idx] = pk;
    }
    __syncthreads();

    // wave handles 32 rows: group0 = lane c, group1 = +16 rows
    const int row0 = blockIdx.x * 128 + wv * 32 + c;
    const float* xr0 = x + (size_t)row0 * 64;
    const float* xr1 = xr0 + 16 * 64;

    unsigned int dpk[2][16][2];  // dd packed bf16 per group (filled by MODE-1 pass)
    f32x4 sx[2][4];              // sqrt2 * x, lane dims 16m+4q+r
    bf16x8 b00, b01, b10, b11;   // bf16 frags of current w
    {
#pragma unroll
        for (int m = 0; m < 4; ++m) {
            f32x4 t0 = *(const f32x4*)(xr0 + 16 * m + 4 * q);
            f32x4 t1 = *(const f32x4*)(xr1 + 16 * m + 4 * q);
#pragma unroll
            for (int r = 0; r < 4; ++r) {
                sx[0][m][r] = SQRT2F * t0[r];
                sx[1][m][r] = SQRT2F * t1[r];
            }
        }
        b00 = packfrag4(sx[0][0], sx[0][1]); b01 = packfrag4(sx[0][2], sx[0][3]);
        b10 = packfrag4(sx[1][0], sx[1][1]); b11 = packfrag4(sx[1][2], sx[1][3]);
    }

    f32x4 g[2][4];
    // ---- fixed-point iterations: w_next = sx - g(w); frags hold w ----
#pragma unroll 1
    for (int it = 0; it < NITER; ++it) {
        fused_pass32<0>(sW1p, sW2p, lane, b00, b01, b10, b11, dpk, g);
        f32x4 w00 = sx[0][0] - g[0][0], w01 = sx[0][1] - g[0][1];
        f32x4 w02 = sx[0][2] - g[0][2], w03 = sx[0][3] - g[0][3];
        f32x4 w10 = sx[1][0] - g[1][0], w11 = sx[1][1] - g[1][1];
        f32x4 w12 = sx[1][2] - g[1][2], w13 = sx[1][3] - g[1][3];
        b00 = packfrag4(w00, w01); b01 = packfrag4(w02, w03);
        b10 = packfrag4(w10, w11); b11 = packfrag4(w12, w13);
    }

    // ---- y = x - sqrt2*g_last = inv_sqrt2*sx - sqrt2*g ----
#pragma unroll
    for (int m = 0; m < 4; ++m) {
        f32x4 y0, y1;
#pragma unroll
        for (int r = 0; r < 4; ++r) {
            y0[r] = fmaf(INVSQRT2F, sx[0][m][r], -SQRT2F * g[0][m][r]);
            y1[r] = fmaf(INVSQRT2F, sx[1][m][r], -SQRT2F * g[1][m][r]);
        }
        *(f32x4*)(out + (size_t)row0 * 64 + 16 * m + 4 * q) = y0;
        *(f32x4*)(out + (size_t)(row0 + 16) * 64 + 16 * m + 4 * q) = y1;
    }

    // ---- dd = sech^2(w_final @ W1); frags already hold w_final ----
    fused_pass32<1>(sW1p, sW2p, lane, b00, b01, b10, b11, dpk, g);

    // ---- Neumann: p = sum_{k odd<=9} eps.(J^k eps); logdet = -2p ----
    f32x4 ew[2][4];
    {
        const float* er0 = eps + (size_t)row0 * 64;
        const float* er1 = er0 + 16 * 64;
#pragma unroll
        for (int m = 0; m < 4; ++m) {
            ew[0][m] = *(const f32x4*)(er0 + 16 * m + 4 * q);
            ew[1][m] = *(const f32x4*)(er1 + 16 * m + 4 * q);
        }
    }
    b00 = packfrag4(ew[0][0], ew[0][1]); b01 = packfrag4(ew[0][2], ew[0][3]);
    b10 = packfrag4(ew[1][0], ew[1][1]); b11 = packfrag4(ew[1][2], ew[1][3]);
    float p0 = 0.f, p1 = 0.f;
#pragma unroll 1
    for (int k = 1; k <= 9; ++k) {
        fused_pass32<2>(sW1p, sW2p, lane, b00, b01, b10, b11, dpk, g);
        if (k & 1) {
#pragma unroll
            for (int m = 0; m < 4; ++m)
#pragma unroll
                for (int r = 0; r < 4; ++r) {
                    p0 = fmaf(ew[0][m][r], g[0][m][r], p0);
                    p1 = fmaf(ew[1][m][r], g[1][m][r], p1);
                }
        }
        b00 = packfrag4(g[0][0], g[0][1]); b01 = packfrag4(g[0][2], g[0][3]);
        b10 = packfrag4(g[1][0], g[1][1]); b11 = packfrag4(g[1][2], g[1][3]);
    }
    p0 += __shfl_xor(p0, 16); p0 += __shfl_xor(p0, 32);
    p1 += __shfl_xor(p1, 16); p1 += __shfl_xor(p1, 32);
    p0 *= -2.0f; p1 *= -2.0f;
    if (lane < 16) {
        out[(size_t)8388608 + row0] = p0;
        out[(size_t)8388608 + row0 + 16] = p1;
    }
}

extern "C" void kernel_launch(void* const* d_in, const int* in_sizes, int n_in,
                              void* d_out, int out_size, void* d_ws, size_t ws_size,
                              hipStream_t stream) {
    const float* x = (const float*)d_in[0];
    const float* eps = (const float*)d_in[1];
    const float* W1 = (const float*)d_in[2];
    const float* W2 = (const float*)d_in[3];
    float* out = (float*)d_out;
    // 131072 rows / (4 waves * 32 rows) = 1024 blocks of 256 threads
    monot_kernel<<<dim3(1024), dim3(256), 0, stream>>>(x, eps, W1, W2, out);
}

// Round 10
// 188.301 us; speedup vs baseline: 7.8359x; 1.3473x over previous
//
#include <hip/hip_runtime.h>

// MonotoneiResBlock: B=131072 rows, D=64, H=256.
//   forward:  w <- sqrt2*x - tanh(w@W1)@W2   (8 iters; Lip~0.49 -> iter err ~1.5e-3 << bf16 floor)
//   y = x - sqrt2*g_last
//   logdet = -2 * sum_{k odd<=9} eps^T J^k eps,   J v = (sech^2(w@W1) o (v@W1)) @ W2
// Transposed MFMA GEMMs, shared K-permutation pi so GEMM1's D-frag feeds GEMM2 as B-frag.
// Round-10 (on top of round-9's spill-free 256t/(256,1)/256-VGPR config):
//   - dd capture folded into LAST forward pass (MODE3): dd at w_7 vs w_8 differs ~2e-4 -> free pass
//   - NITER 10 -> 8 : passes 21 -> 17
//   - all f32->bf16 packing via v_cvt_pk_bf16_f32 (1 inst vs 4 bit-ops; gfx950-verified primitive)
// d_out FLOAT32: y = 131072*64, then logdet = 131072.

typedef __attribute__((ext_vector_type(8))) short bf16x8;
typedef __attribute__((ext_vector_type(4))) float f32x4;
typedef __attribute__((ext_vector_type(4))) unsigned int u32x4;

#define SQRT2F 1.41421356237309515f
#define INVSQRT2F 0.70710678118654752f
#define NITER 8

__device__ __forceinline__ unsigned int cvtpk(float lo, float hi) {
    unsigned int r;
    asm("v_cvt_pk_bf16_f32 %0, %1, %2" : "=v"(r) : "v"(lo), "v"(hi));
    return r;
}
__device__ __forceinline__ float bf_lo(unsigned int u) { return __builtin_bit_cast(float, u << 16); }
__device__ __forceinline__ float bf_hi(unsigned int u) { return __builtin_bit_cast(float, u & 0xFFFF0000u); }
__device__ __forceinline__ float fast_tanh(float xx) {
    float a = __expf(xx + xx);
    float r = __builtin_amdgcn_rcpf(a + 1.0f);
    return fmaf(-2.0f, r, 1.0f);
}
__device__ __forceinline__ bf16x8 packfrag4(f32x4 a, f32x4 b) {
    u32x4 r;
    r[0] = cvtpk(a[0], a[1]); r[1] = cvtpk(a[2], a[3]);
    r[2] = cvtpk(b[0], b[1]); r[3] = cvtpk(b[2], b[3]);
    return __builtin_bit_cast(bf16x8, r);
}

// Fused pass over 32 rows (two 16-row groups share every weight A-frag ds_read).
// MODE 0: tanh. MODE 3: tanh + capture dd. MODE 2: dd-multiply. All run GEMM2.
template <int MODE>
__device__ __forceinline__ void fused_pass32(const u32x4* __restrict__ sW1p, const u32x4* __restrict__ sW2p,
                                             int lane, bf16x8 b00, bf16x8 b01, bf16x8 b10, bf16x8 b11,
                                             unsigned int (&dpk)[2][16][2], f32x4 (&g)[2][4]) {
    f32x4 zz = {0.f, 0.f, 0.f, 0.f};
#pragma unroll
    for (int gi = 0; gi < 2; ++gi)
#pragma unroll
        for (int t = 0; t < 4; ++t) g[gi][t] = zz;
#pragma unroll
    for (int kk = 0; kk < 8; ++kk) {
        u32x4 hbk0, hbk1;
#pragma unroll
        for (int sub = 0; sub < 2; ++sub) {
            const int m = 2 * kk + sub;
            u32x4 wA = sW1p[(m * 2 + 0) * 64 + lane];
            u32x4 wB = sW1p[(m * 2 + 1) * 64 + lane];
            f32x4 a0 = zz, a1 = zz;
            a0 = __builtin_amdgcn_mfma_f32_16x16x32_bf16(__builtin_bit_cast(bf16x8, wA), b00, a0, 0, 0, 0);
            a0 = __builtin_amdgcn_mfma_f32_16x16x32_bf16(__builtin_bit_cast(bf16x8, wB), b01, a0, 0, 0, 0);
            a1 = __builtin_amdgcn_mfma_f32_16x16x32_bf16(__builtin_bit_cast(bf16x8, wA), b10, a1, 0, 0, 0);
            a1 = __builtin_amdgcn_mfma_f32_16x16x32_bf16(__builtin_bit_cast(bf16x8, wB), b11, a1, 0, 0, 0);
            float h00, h01, h02, h03, h10, h11, h12, h13;
            if constexpr (MODE == 2) {
                h00 = a0[0] * bf_lo(dpk[0][m][0]);
                h01 = a0[1] * bf_hi(dpk[0][m][0]);
                h02 = a0[2] * bf_lo(dpk[0][m][1]);
                h03 = a0[3] * bf_hi(dpk[0][m][1]);
                h10 = a1[0] * bf_lo(dpk[1][m][0]);
                h11 = a1[1] * bf_hi(dpk[1][m][0]);
                h12 = a1[2] * bf_lo(dpk[1][m][1]);
                h13 = a1[3] * bf_hi(dpk[1][m][1]);
            } else {
                h00 = fast_tanh(a0[0]); h01 = fast_tanh(a0[1]);
                h02 = fast_tanh(a0[2]); h03 = fast_tanh(a0[3]);
                h10 = fast_tanh(a1[0]); h11 = fast_tanh(a1[1]);
                h12 = fast_tanh(a1[2]); h13 = fast_tanh(a1[3]);
                if constexpr (MODE == 3) {
                    dpk[0][m][0] = cvtpk(fmaf(-h00, h00, 1.0f), fmaf(-h01, h01, 1.0f));
                    dpk[0][m][1] = cvtpk(fmaf(-h02, h02, 1.0f), fmaf(-h03, h03, 1.0f));
                    dpk[1][m][0] = cvtpk(fmaf(-h10, h10, 1.0f), fmaf(-h11, h11, 1.0f));
                    dpk[1][m][1] = cvtpk(fmaf(-h12, h12, 1.0f), fmaf(-h13, h13, 1.0f));
                }
            }
            hbk0[2 * sub + 0] = cvtpk(h00, h01); hbk0[2 * sub + 1] = cvtpk(h02, h03);
            hbk1[2 * sub + 0] = cvtpk(h10, h11); hbk1[2 * sub + 1] = cvtpk(h12, h13);
        }
        bf16x8 bh0 = __builtin_bit_cast(bf16x8, hbk0);
        bf16x8 bh1 = __builtin_bit_cast(bf16x8, hbk1);
#pragma unroll
        for (int t = 0; t < 4; ++t) {
            bf16x8 w2 = __builtin_bit_cast(bf16x8, sW2p[(t * 8 + kk) * 64 + lane]);
            g[0][t] = __builtin_amdgcn_mfma_f32_16x16x32_bf16(w2, bh0, g[0][t], 0, 0, 0);
            g[1][t] = __builtin_amdgcn_mfma_f32_16x16x32_bf16(w2, bh1, g[1][t], 0, 0, 0);
        }
    }
}

__global__ __launch_bounds__(256, 1) void monot_kernel(
    const float* __restrict__ x, const float* __restrict__ eps,
    const float* __restrict__ W1, const float* __restrict__ W2,
    float* __restrict__ out) {
    __shared__ u32x4 sW1p[2048];  // [m0(16)][kk(2)][lane(64)] A-frags of W1^T, pi-permuted K
    __shared__ u32x4 sW2p[2048];  // [m0(4)][kk(8)][lane(64)]  A-frags of W2^T

    const int tid = threadIdx.x;
    const int lane = tid & 63;
    const int wv = tid >> 6;  // 0..3
    const int c = lane & 15;
    const int q = lane >> 4;

    // ---- pack weights into LDS (A-frag layout; pi(q,j) = 4q + (j&3) + 16*(j>>2)) ----
#pragma unroll
    for (int e0 = 0; e0 < 8; ++e0) {
        int idx = e0 * 256 + tid;  // W1 entries
        int l = idx & 63;
        int lq = l >> 4, lc = l & 15;
        int m0 = idx >> 7;
        int kk = (idx >> 6) & 1;
        float v[8];
#pragma unroll
        for (int j = 0; j < 8; ++j) {
            int kp = 32 * kk + 4 * lq + (j & 3) + ((j >> 2) << 4);
            v[j] = W1[kp * 256 + 16 * m0 + lc];  // W1^T[16m0+lc][kp]
        }
        u32x4 pk;
        pk[0] = cvtpk(v[0], v[1]); pk[1] = cvtpk(v[2], v[3]);
        pk[2] = cvtpk(v[4], v[5]); pk[3] = cvtpk(v[6], v[7]);
        sW1p[idx] = pk;
    }
#pragma unroll
    for (int e0 = 0; e0 < 8; ++e0) {
        int idx = e0 * 256 + tid;  // W2 entries
        int l = idx & 63;
        int lq = l >> 4, lc = l & 15;
        int m0 = idx >> 9;
        int kk = (idx >> 6) & 7;
        float v[8];
#pragma unroll
        for (int j = 0; j < 8; ++j) {
            int kp = 32 * kk + 4 * lq + (j & 3) + ((j >> 2) << 4);
            v[j] = W2[kp * 64 + 16 * m0 + lc];  // W2^T[16m0+lc][kp]
        }
        u32x4 pk;
        pk[0] = cvtpk(v[0], v[1]); pk[1] = cvtpk(v[2], v[3]);
        pk[2] = cvtpk(v[4], v[5]); pk[3] = cvtpk(v[6], v[7]);
        sW2p[idx] = pk;
    }
    __syncthreads();

    // wave handles 32 rows: group0 = lane c, group1 = +16 rows
    const int row0 = blockIdx.x * 128 + wv * 32 + c;
    const float* xr0 = x + (size_t)row0 * 64;
    const float* xr1 = xr0 + 16 * 64;

    unsigned int dpk[2][16][2];  // dd packed bf16 per group (captured by MODE-3 pass)
    f32x4 sx[2][4];              // sqrt2 * x, lane dims 16m+4q+r
    bf16x8 b00, b01, b10, b11;   // bf16 frags of current w
    {
#pragma unroll
        for (int m = 0; m < 4; ++m) {
            f32x4 t0 = *(const f32x4*)(xr0 + 16 * m + 4 * q);
            f32x4 t1 = *(const f32x4*)(xr1 + 16 * m + 4 * q);
#pragma unroll
            for (int r = 0; r < 4; ++r) {
                sx[0][m][r] = SQRT2F * t0[r];
                sx[1][m][r] = SQRT2F * t1[r];
            }
        }
        b00 = packfrag4(sx[0][0], sx[0][1]); b01 = packfrag4(sx[0][2], sx[0][3]);
        b10 = packfrag4(sx[1][0], sx[1][1]); b11 = packfrag4(sx[1][2], sx[1][3]);
    }

    f32x4 g[2][4];
    // ---- fixed-point iterations (last one also captures dd at w_{NITER-1}) ----
#pragma unroll 1
    for (int it = 0; it < NITER - 1; ++it) {
        fused_pass32<0>(sW1p, sW2p, lane, b00, b01, b10, b11, dpk, g);
        f32x4 w00 = sx[0][0] - g[0][0], w01 = sx[0][1] - g[0][1];
        f32x4 w02 = sx[0][2] - g[0][2], w03 = sx[0][3] - g[0][3];
        f32x4 w10 = sx[1][0] - g[1][0], w11 = sx[1][1] - g[1][1];
        f32x4 w12 = sx[1][2] - g[1][2], w13 = sx[1][3] - g[1][3];
        b00 = packfrag4(w00, w01); b01 = packfrag4(w02, w03);
        b10 = packfrag4(w10, w11); b11 = packfrag4(w12, w13);
    }
    fused_pass32<3>(sW1p, sW2p, lane, b00, b01, b10, b11, dpk, g);

    // ---- y = x - sqrt2*g_last = inv_sqrt2*sx - sqrt2*g ----
#pragma unroll
    for (int m = 0; m < 4; ++m) {
        f32x4 y0, y1;
#pragma unroll
        for (int r = 0; r < 4; ++r) {
            y0[r] = fmaf(INVSQRT2F, sx[0][m][r], -SQRT2F * g[0][m][r]);
            y1[r] = fmaf(INVSQRT2F, sx[1][m][r], -SQRT2F * g[1][m][r]);
        }
        *(f32x4*)(out + (size_t)row0 * 64 + 16 * m + 4 * q) = y0;
        *(f32x4*)(out + (size_t)(row0 + 16) * 64 + 16 * m + 4 * q) = y1;
    }

    // ---- Neumann: p = sum_{k odd<=9} eps.(J^k eps); logdet = -2p ----
    f32x4 ew[2][4];
    {
        const float* er0 = eps + (size_t)row0 * 64;
        const float* er1 = er0 + 16 * 64;
#pragma unroll
        for (int m = 0; m < 4; ++m) {
            ew[0][m] = *(const f32x4*)(er0 + 16 * m + 4 * q);
            ew[1][m] = *(const f32x4*)(er1 + 16 * m + 4 * q);
        }
    }
    b00 = packfrag4(ew[0][0], ew[0][1]); b01 = packfrag4(ew[0][2], ew[0][3]);
    b10 = packfrag4(ew[1][0], ew[1][1]); b11 = packfrag4(ew[1][2], ew[1][3]);
    float p0 = 0.f, p1 = 0.f;
#pragma unroll 1
    for (int k = 1; k <= 9; ++k) {
        fused_pass32<2>(sW1p, sW2p, lane, b00, b01, b10, b11, dpk, g);
        if (k & 1) {
#pragma unroll
            for (int m = 0; m < 4; ++m)
#pragma unroll
                for (int r = 0; r < 4; ++r) {
                    p0 = fmaf(ew[0][m][r], g[0][m][r], p0);
                    p1 = fmaf(ew[1][m][r], g[1][m][r], p1);
                }
        }
        b00 = packfrag4(g[0][0], g[0][1]); b01 = packfrag4(g[0][2], g[0][3]);
        b10 = packfrag4(g[1][0], g[1][1]); b11 = packfrag4(g[1][2], g[1][3]);
    }
    p0 += __shfl_xor(p0, 16); p0 += __shfl_xor(p0, 32);
    p1 += __shfl_xor(p1, 16); p1 += __shfl_xor(p1, 32);
    p0 *= -2.0f; p1 *= -2.0f;
    if (lane < 16) {
        out[(size_t)8388608 + row0] = p0;
        out[(size_t)8388608 + row0 + 16] = p1;
    }
}

extern "C" void kernel_launch(void* const* d_in, const int* in_sizes, int n_in,
                              void* d_out, int out_size, void* d_ws, size_t ws_size,
                              hipStream_t stream) {
    const float* x = (const float*)d_in[0];
    const float* eps = (const float*)d_in[1];
    const float* W1 = (const float*)d_in[2];
    const float* W2 = (const float*)d_in[3];
    float* out = (float*)d_out;
    // 131072 rows / (4 waves * 32 rows) = 1024 blocks of 256 threads
    monot_kernel<<<dim3(1024), dim3(256), 0, stream>>>(x, eps, W1, W2, out);
}

// Round 12
// 172.905 us; speedup vs baseline: 8.5336x; 1.0890x over previous
//
#include <hip/hip_runtime.h>

// MonotoneiResBlock: B=131072 rows, D=64, H=256.
//   forward:  w <- sqrt2*x - tanh(w@W1)@W2   (7 iters; Lip~0.49 -> worst-row err ~0.03 << 0.186)
//   y = x - sqrt2*g_last
//   logdet = -2 * sum_{k odd<=9} eps^T J^k eps,   J v = (sech^2(w@W1) o (v@W1)) @ W2
// Transposed MFMA GEMMs, shared K-permutation pi so GEMM1's D-frag feeds GEMM2 as B-frag.
// Round-12: revert round-11's raw v_exp asm (TRANS-hazard: compiler can't insert the required wait
// state around inline asm -> stale reads -> divergence). Base = verified round-10 (188us). New:
//   - Pade[7/5] tanh with fmed3 +-4 clamp, written on f32x2 (compiler forms v_pk_fma_f32):
//     2 TRANS (rcp) per pair instead of 4 (exp+rcp); no exp anywhere.
//   - NITER 8 -> 7.
// d_out FLOAT32: y = 131072*64, then logdet = 131072.

typedef __attribute__((ext_vector_type(8))) short bf16x8;
typedef __attribute__((ext_vector_type(4))) float f32x4;
typedef __attribute__((ext_vector_type(2))) float f32x2;
typedef __attribute__((ext_vector_type(4))) unsigned int u32x4;

#define SQRT2F 1.41421356237309515f
#define INVSQRT2F 0.70710678118654752f
#define NITER 7

__device__ __forceinline__ unsigned int cvtpk(float lo, float hi) {
    unsigned int r;
    asm("v_cvt_pk_bf16_f32 %0, %1, %2" : "=v"(r) : "v"(lo), "v"(hi));
    return r;
}
__device__ __forceinline__ float bf_lo(unsigned int u) { return __builtin_bit_cast(float, u << 16); }
__device__ __forceinline__ float bf_hi(unsigned int u) { return __builtin_bit_cast(float, u & 0xFFFF0000u); }

// Pade[7/5] tanh on a pair: tanh(x) ~ x(945+105x^2+x^4)/(945+420x^2+15x^4), |x| clamped to 4.
// err < 2.5e-3 at clamp, ~1e-6 for |x|<2. Only TRANS is rcp (builtin -> hazard-safe).
__device__ __forceinline__ f32x2 tanh2(float xa, float xb) {
    f32x2 x;
    x[0] = __builtin_amdgcn_fmed3f(xa, -4.0f, 4.0f);
    x[1] = __builtin_amdgcn_fmed3f(xb, -4.0f, 4.0f);
    f32x2 x2 = x * x;
    f32x2 n = x2 * (x2 + 105.0f) + 945.0f;
    f32x2 d = x2 * (x2 * 15.0f + 420.0f) + 945.0f;
    f32x2 r;
    r[0] = __builtin_amdgcn_rcpf(d[0]);
    r[1] = __builtin_amdgcn_rcpf(d[1]);
    return (x * n) * r;
}
__device__ __forceinline__ bf16x8 packfrag4(f32x4 a, f32x4 b) {
    u32x4 r;
    r[0] = cvtpk(a[0], a[1]); r[1] = cvtpk(a[2], a[3]);
    r[2] = cvtpk(b[0], b[1]); r[3] = cvtpk(b[2], b[3]);
    return __builtin_bit_cast(bf16x8, r);
}

// Fused pass over 32 rows (two 16-row groups share every weight A-frag ds_read).
// MODE 0: tanh. MODE 3: tanh + capture dd. MODE 2: dd-multiply. All run GEMM2.
template <int MODE>
__device__ __forceinline__ void fused_pass32(const u32x4* __restrict__ sW1p, const u32x4* __restrict__ sW2p,
                                             int lane, bf16x8 b00, bf16x8 b01, bf16x8 b10, bf16x8 b11,
                                             unsigned int (&dpk)[2][16][2], f32x4 (&g)[2][4]) {
    f32x4 zz = {0.f, 0.f, 0.f, 0.f};
#pragma unroll
    for (int gi = 0; gi < 2; ++gi)
#pragma unroll
        for (int t = 0; t < 4; ++t) g[gi][t] = zz;
#pragma unroll
    for (int kk = 0; kk < 8; ++kk) {
        u32x4 hbk0, hbk1;
#pragma unroll
        for (int sub = 0; sub < 2; ++sub) {
            const int m = 2 * kk + sub;
            u32x4 wA = sW1p[(m * 2 + 0) * 64 + lane];
            u32x4 wB = sW1p[(m * 2 + 1) * 64 + lane];
            f32x4 a0 = zz, a1 = zz;
            a0 = __builtin_amdgcn_mfma_f32_16x16x32_bf16(__builtin_bit_cast(bf16x8, wA), b00, a0, 0, 0, 0);
            a0 = __builtin_amdgcn_mfma_f32_16x16x32_bf16(__builtin_bit_cast(bf16x8, wB), b01, a0, 0, 0, 0);
            a1 = __builtin_amdgcn_mfma_f32_16x16x32_bf16(__builtin_bit_cast(bf16x8, wA), b10, a1, 0, 0, 0);
            a1 = __builtin_amdgcn_mfma_f32_16x16x32_bf16(__builtin_bit_cast(bf16x8, wB), b11, a1, 0, 0, 0);
            if constexpr (MODE == 2) {
                float h00 = a0[0] * bf_lo(dpk[0][m][0]);
                float h01 = a0[1] * bf_hi(dpk[0][m][0]);
                float h02 = a0[2] * bf_lo(dpk[0][m][1]);
                float h03 = a0[3] * bf_hi(dpk[0][m][1]);
                float h10 = a1[0] * bf_lo(dpk[1][m][0]);
                float h11 = a1[1] * bf_hi(dpk[1][m][0]);
                float h12 = a1[2] * bf_lo(dpk[1][m][1]);
                float h13 = a1[3] * bf_hi(dpk[1][m][1]);
                hbk0[2 * sub + 0] = cvtpk(h00, h01); hbk0[2 * sub + 1] = cvtpk(h02, h03);
                hbk1[2 * sub + 0] = cvtpk(h10, h11); hbk1[2 * sub + 1] = cvtpk(h12, h13);
            } else {
                f32x2 h0a = tanh2(a0[0], a0[1]);
                f32x2 h0b = tanh2(a0[2], a0[3]);
                f32x2 h1a = tanh2(a1[0], a1[1]);
                f32x2 h1b = tanh2(a1[2], a1[3]);
                if constexpr (MODE == 3) {
                    f32x2 d0a = 1.0f - h0a * h0a;
                    f32x2 d0b = 1.0f - h0b * h0b;
                    f32x2 d1a = 1.0f - h1a * h1a;
                    f32x2 d1b = 1.0f - h1b * h1b;
                    dpk[0][m][0] = cvtpk(d0a[0], d0a[1]);
                    dpk[0][m][1] = cvtpk(d0b[0], d0b[1]);
                    dpk[1][m][0] = cvtpk(d1a[0], d1a[1]);
                    dpk[1][m][1] = cvtpk(d1b[0], d1b[1]);
                }
                hbk0[2 * sub + 0] = cvtpk(h0a[0], h0a[1]); hbk0[2 * sub + 1] = cvtpk(h0b[0], h0b[1]);
                hbk1[2 * sub + 0] = cvtpk(h1a[0], h1a[1]); hbk1[2 * sub + 1] = cvtpk(h1b[0], h1b[1]);
            }
        }
        bf16x8 bh0 = __builtin_bit_cast(bf16x8, hbk0);
        bf16x8 bh1 = __builtin_bit_cast(bf16x8, hbk1);
#pragma unroll
        for (int t = 0; t < 4; ++t) {
            bf16x8 w2 = __builtin_bit_cast(bf16x8, sW2p[(t * 8 + kk) * 64 + lane]);
            g[0][t] = __builtin_amdgcn_mfma_f32_16x16x32_bf16(w2, bh0, g[0][t], 0, 0, 0);
            g[1][t] = __builtin_amdgcn_mfma_f32_16x16x32_bf16(w2, bh1, g[1][t], 0, 0, 0);
        }
    }
}

__global__ __launch_bounds__(256, 1) void monot_kernel(
    const float* __restrict__ x, const float* __restrict__ eps,
    const float* __restrict__ W1, const float* __restrict__ W2,
    float* __restrict__ out) {
    __shared__ u32x4 sW1p[2048];  // [m0(16)][kk(2)][lane(64)] A-frags of W1^T, pi-permuted K
    __shared__ u32x4 sW2p[2048];  // [m0(4)][kk(8)][lane(64)]  A-frags of W2^T

    const int tid = threadIdx.x;
    const int lane = tid & 63;
    const int wv = tid >> 6;  // 0..3
    const int c = lane & 15;
    const int q = lane >> 4;

    // ---- pack weights into LDS (A-frag layout; pi(q,j) = 4q + (j&3) + 16*(j>>2)) ----
#pragma unroll
    for (int e0 = 0; e0 < 8; ++e0) {
        int idx = e0 * 256 + tid;  // W1 entries
        int l = idx & 63;
        int lq = l >> 4, lc = l & 15;
        int m0 = idx >> 7;
        int kk = (idx >> 6) & 1;
        float v[8];
#pragma unroll
        for (int j = 0; j < 8; ++j) {
            int kp = 32 * kk + 4 * lq + (j & 3) + ((j >> 2) << 4);
            v[j] = W1[kp * 256 + 16 * m0 + lc];  // W1^T[16m0+lc][kp]
        }
        u32x4 pk;
        pk[0] = cvtpk(v[0], v[1]); pk[1] = cvtpk(v[2], v[3]);
        pk[2] = cvtpk(v[4], v[5]); pk[3] = cvtpk(v[6], v[7]);
        sW1p[idx] = pk;
    }
#pragma unroll
    for (int e0 = 0; e0 < 8; ++e0) {
        int idx = e0 * 256 + tid;  // W2 entries
        int l = idx & 63;
        int lq = l >> 4, lc = l & 15;
        int m0 = idx >> 9;
        int kk = (idx >> 6) & 7;
        float v[8];
#pragma unroll
        for (int j = 0; j < 8; ++j) {
            int kp = 32 * kk + 4 * lq + (j & 3) + ((j >> 2) << 4);
            v[j] = W2[kp * 64 + 16 * m0 + lc];  // W2^T[16m0+lc][kp]
        }
        u32x4 pk;
        pk[0] = cvtpk(v[0], v[1]); pk[1] = cvtpk(v[2], v[3]);
        pk[2] = cvtpk(v[4], v[5]); pk[3] = cvtpk(v[6], v[7]);
        sW2p[idx] = pk;
    }
    __syncthreads();

    // wave handles 32 rows: group0 = lane c, group1 = +16 rows
    const int row0 = blockIdx.x * 128 + wv * 32 + c;
    const float* xr0 = x + (size_t)row0 * 64;
    const float* xr1 = xr0 + 16 * 64;

    unsigned int dpk[2][16][2];  // dd packed bf16 per group (captured by MODE-3 pass)
    f32x4 sx[2][4];              // sqrt2 * x, lane dims 16m+4q+r
    bf16x8 b00, b01, b10, b11;   // bf16 frags of current w
    {
#pragma unroll
        for (int m = 0; m < 4; ++m) {
            f32x4 t0 = *(const f32x4*)(xr0 + 16 * m + 4 * q);
            f32x4 t1 = *(const f32x4*)(xr1 + 16 * m + 4 * q);
#pragma unroll
            for (int r = 0; r < 4; ++r) {
                sx[0][m][r] = SQRT2F * t0[r];
                sx[1][m][r] = SQRT2F * t1[r];
            }
        }
        b00 = packfrag4(sx[0][0], sx[0][1]); b01 = packfrag4(sx[0][2], sx[0][3]);
        b10 = packfrag4(sx[1][0], sx[1][1]); b11 = packfrag4(sx[1][2], sx[1][3]);
    }

    f32x4 g[2][4];
    // ---- fixed-point iterations (last one also captures dd at w_{NITER-1}) ----
#pragma unroll 1
    for (int it = 0; it < NITER - 1; ++it) {
        fused_pass32<0>(sW1p, sW2p, lane, b00, b01, b10, b11, dpk, g);
        f32x4 w00 = sx[0][0] - g[0][0], w01 = sx[0][1] - g[0][1];
        f32x4 w02 = sx[0][2] - g[0][2], w03 = sx[0][3] - g[0][3];
        f32x4 w10 = sx[1][0] - g[1][0], w11 = sx[1][1] - g[1][1];
        f32x4 w12 = sx[1][2] - g[1][2], w13 = sx[1][3] - g[1][3];
        b00 = packfrag4(w00, w01); b01 = packfrag4(w02, w03);
        b10 = packfrag4(w10, w11); b11 = packfrag4(w12, w13);
    }
    fused_pass32<3>(sW1p, sW2p, lane, b00, b01, b10, b11, dpk, g);

    // ---- y = x - sqrt2*g_last = inv_sqrt2*sx - sqrt2*g ----
#pragma unroll
    for (int m = 0; m < 4; ++m) {
        f32x4 y0, y1;
#pragma unroll
        for (int r = 0; r < 4; ++r) {
            y0[r] = fmaf(INVSQRT2F, sx[0][m][r], -SQRT2F * g[0][m][r]);
            y1[r] = fmaf(INVSQRT2F, sx[1][m][r], -SQRT2F * g[1][m][r]);
        }
        *(f32x4*)(out + (size_t)row0 * 64 + 16 * m + 4 * q) = y0;
        *(f32x4*)(out + (size_t)(row0 + 16) * 64 + 16 * m + 4 * q) = y1;
    }

    // ---- Neumann: p = sum_{k odd<=9} eps.(J^k eps); logdet = -2p ----
    f32x4 ew[2][4];
    {
        const float* er0 = eps + (size_t)row0 * 64;
        const float* er1 = er0 + 16 * 64;
#pragma unroll
        for (int m = 0; m < 4; ++m) {
            ew[0][m] = *(const f32x4*)(er0 + 16 * m + 4 * q);
            ew[1][m] = *(const f32x4*)(er1 + 16 * m + 4 * q);
        }
    }
    b00 = packfrag4(ew[0][0], ew[0][1]); b01 = packfrag4(ew[0][2], ew[0][3]);
    b10 = packfrag4(ew[1][0], ew[1][1]); b11 = packfrag4(ew[1][2], ew[1][3]);
    float p0 = 0.f, p1 = 0.f;
#pragma unroll 1
    for (int k = 1; k <= 9; ++k) {
        fused_pass32<2>(sW1p, sW2p, lane, b00, b01, b10, b11, dpk, g);
        if (k & 1) {
#pragma unroll
            for (int m = 0; m < 4; ++m)
#pragma unroll
                for (int r = 0; r < 4; ++r) {
                    p0 = fmaf(ew[0][m][r], g[0][m][r], p0);
                    p1 = fmaf(ew[1][m][r], g[1][m][r], p1);
                }
        }
        b00 = packfrag4(g[0][0], g[0][1]); b01 = packfrag4(g[0][2], g[0][3]);
        b10 = packfrag4(g[1][0], g[1][1]); b11 = packfrag4(g[1][2], g[1][3]);
    }
    p0 += __shfl_xor(p0, 16); p0 += __shfl_xor(p0, 32);
    p1 += __shfl_xor(p1, 16); p1 += __shfl_xor(p1, 32);
    p0 *= -2.0f; p1 *= -2.0f;
    if (lane < 16) {
        out[(size_t)8388608 + row0] = p0;
        out[(size_t)8388608 + row0 + 16] = p1;
    }
}

extern "C" void kernel_launch(void* const* d_in, const int* in_sizes, int n_in,
                              void* d_out, int out_size, void* d_ws, size_t ws_size,
                              hipStream_t stream) {
    const float* x = (const float*)d_in[0];
    const float* eps = (const float*)d_in[1];
    const float* W1 = (const float*)d_in[2];
    const float* W2 = (const float*)d_in[3];
    float* out = (float*)d_out;
    // 131072 rows / (4 waves * 32 rows) = 1024 blocks of 256 threads
    monot_kernel<<<dim3(1024), dim3(256), 0, stream>>>(x, eps, W1, W2, out);
}